// Round 5
// baseline (351.946 us; speedup 1.0000x reference)
//
#include <hip/hip_runtime.h>
#include <math.h>

// Problem constants (from reference): B=4096 segments, D=256 features, O=4 outputs.
#define SCAN_DIM 256
#define NWAVES   4096   // balanced pass-A waves (one 64-thread block each)

typedef float v4f __attribute__((ext_vector_type(4)));

// ---------------------------------------------------------------------------
// Kernel 1: exclusive prefix sum of counts -> offsets[0..B] (offsets[B]=T),
// plus zero-init of the 64 KB seg_acc staging buffer. Single block, ~5 us.
// ---------------------------------------------------------------------------
__global__ void seg_offsets_kernel(const int* __restrict__ counts,
                                   int* __restrict__ offsets,
                                   float* __restrict__ seg_acc, int B) {
  __shared__ int partial[SCAN_DIM];
  const int tid = threadIdx.x;
  const int chunk = (B + SCAN_DIM - 1) / SCAN_DIM;   // 16 for B=4096
  const int base = tid * chunk;

  int s = 0;
  for (int i = 0; i < chunk; ++i) {
    const int idx = base + i;
    if (idx < B) s += counts[idx];
  }
  partial[tid] = s;
  __syncthreads();

  for (int off = 1; off < SCAN_DIM; off <<= 1) {
    int v = (tid >= off) ? partial[tid - off] : 0;
    __syncthreads();
    partial[tid] += v;
    __syncthreads();
  }

  int run = (tid == 0) ? 0 : partial[tid - 1];  // exclusive base for this chunk
  for (int i = 0; i < chunk; ++i) {
    const int idx = base + i;
    if (idx < B) {
      offsets[idx] = run;
      run += counts[idx];
    }
  }
  if (tid == SCAN_DIM - 1) offsets[B] = run;    // total node count T

  for (int i = tid; i < B * 4; i += SCAN_DIM) seg_acc[i] = 0.0f;
}

// ---------------------------------------------------------------------------
// Kernel 2 (pass A): PERFECTLY BALANCED projection-accumulate.
// Wave w owns rows [w*chunk, min((w+1)*chunk, T)) regardless of segment
// boundaries (uniform ~64 rows/wave -> no straggler CUs). It accumulates
// x-row dot W across its range and flushes (butterfly reduce + 4 atomicAdds
// into seg_acc) whenever it crosses a segment boundary (2-3 flushes/wave,
// segments are >=32 rows). Streaming loads stay NT + software-pipelined.
// ---------------------------------------------------------------------------
__global__ __launch_bounds__(64) void proj_acc_kernel(
    const float* __restrict__ x, const int* __restrict__ offsets,
    const float* __restrict__ W, float* __restrict__ seg_acc,
    int B, int T, int chunk) {
  const int wave = blockIdx.x;
  const int lane = threadIdx.x;           // 0..63
  const int r0 = wave * chunk;
  if (r0 >= T) return;
  const int r1 = min(r0 + chunk, T);

  // Each lane owns features [4*lane, 4*lane+4). W is [4][256] row-major.
  const v4f* W4 = (const v4f*)W;
  const v4f w0 = W4[0 * 64 + lane];
  const v4f w1 = W4[1 * 64 + lane];
  const v4f w2 = W4[2 * 64 + lane];
  const v4f w3 = W4[3 * 64 + lane];

  // Binary search: seg = max s with offsets[s] <= r0  (offsets has B+1 entries)
  int lo = 0, hi = B;
  while (hi - lo > 1) {
    const int mid = (lo + hi) >> 1;
    if (offsets[mid] <= r0) lo = mid; else hi = mid;
  }
  int seg    = lo;
  int segEnd = offsets[seg + 1];

  float a0 = 0.f, a1 = 0.f, a2 = 0.f, a3 = 0.f;

  // Flush current accumulators into seg_acc[seg] (wave-uniform call sites).
  auto flush = [&]() {
    float t0 = a0, t1 = a1, t2 = a2, t3 = a3;
    for (int off = 32; off > 0; off >>= 1) {
      t0 += __shfl_down(t0, off, 64);
      t1 += __shfl_down(t1, off, 64);
      t2 += __shfl_down(t2, off, 64);
      t3 += __shfl_down(t3, off, 64);
    }
    if (lane == 0) {
      atomicAdd(&seg_acc[seg * 4 + 0], t0);
      atomicAdd(&seg_acc[seg * 4 + 1], t1);
      atomicAdd(&seg_acc[seg * 4 + 2], t2);
      atomicAdd(&seg_acc[seg * 4 + 3], t3);
    }
    a0 = a1 = a2 = a3 = 0.f;
  };

#define ACC(v)                                                      \
  a0 += (v).x * w0.x + (v).y * w0.y + (v).z * w0.z + (v).w * w0.w;  \
  a1 += (v).x * w1.x + (v).y * w1.y + (v).z * w1.z + (v).w * w1.w;  \
  a2 += (v).x * w2.x + (v).y * w2.y + (v).z * w2.z + (v).w * w2.w;  \
  a3 += (v).x * w3.x + (v).y * w3.y + (v).z * w3.z + (v).w * w3.w;

#define BOUNDARY(r)                                                 \
  if ((r) == segEnd) { flush(); ++seg; segEnd = offsets[seg + 1]; }

  // Row r = 64 v4f; this lane's slice of row r0 at p[0].
  const v4f* xb = (const v4f*)x + (long)r0 * 64 + lane;
  const v4f* p  = xb;

  int n = r0;
  v4f v0, v1, v2, v3;
  bool have = (n + 3 < r1);               // wave-uniform
  if (have) {
    v0 = __builtin_nontemporal_load(p + 0);
    v1 = __builtin_nontemporal_load(p + 64);
    v2 = __builtin_nontemporal_load(p + 128);
    v3 = __builtin_nontemporal_load(p + 192);
  }
  while (have) {
    const int  nn   = n + 4;
    const bool next = (nn + 3 < r1);      // wave-uniform
    const v4f* q    = p + 256;            // +4 rows = 4 KB
    v4f u0, u1, u2, u3;
    if (next) {                           // prefetch next group before FMAs
      u0 = __builtin_nontemporal_load(q + 0);
      u1 = __builtin_nontemporal_load(q + 64);
      u2 = __builtin_nontemporal_load(q + 128);
      u3 = __builtin_nontemporal_load(q + 192);
    }

    BOUNDARY(n + 0) ACC(v0)
    BOUNDARY(n + 1) ACC(v1)
    BOUNDARY(n + 2) ACC(v2)
    BOUNDARY(n + 3) ACC(v3)

    if (next) { v0 = u0; v1 = u1; v2 = u2; v3 = u3; }
    p = q; n = nn; have = next;
  }
  // Tail: <=3 rows.
  for (; n < r1; ++n) {
    BOUNDARY(n)
    const v4f v = __builtin_nontemporal_load(xb + (long)(n - r0) * 64);
    ACC(v)
  }
  flush();                                // remainder belongs to current seg

#undef ACC
#undef BOUNDARY
}

// ---------------------------------------------------------------------------
// Kernel 3 (pass B): per-segment mean + bias + sigmoid. 64 KB traffic, ~2 us.
// ---------------------------------------------------------------------------
__global__ void finish_kernel(const float* __restrict__ seg_acc,
                              const int* __restrict__ counts,
                              const float* __restrict__ b,
                              float* __restrict__ out, int B) {
  const int i = blockIdx.x * blockDim.x + threadIdx.x;
  if (i >= B) return;
  const v4f acc = ((const v4f*)seg_acc)[i];
  const float inv = 1.0f / (float)counts[i];
  v4f r;
  r.x = 1.0f / (1.0f + expf(-(acc.x * inv + b[0])));
  r.y = 1.0f / (1.0f + expf(-(acc.y * inv + b[1])));
  r.z = 1.0f / (1.0f + expf(-(acc.z * inv + b[2])));
  r.w = 1.0f / (1.0f + expf(-(acc.w * inv + b[3])));
  ((v4f*)out)[i] = r;
}

// ---------------------------------------------------------------------------
extern "C" void kernel_launch(void* const* d_in, const int* in_sizes, int n_in,
                              void* d_out, int out_size, void* d_ws, size_t ws_size,
                              hipStream_t stream) {
  const float* x        = (const float*)d_in[0];
  const int*   node_num = (const int*)d_in[1];   // int32 on device (JAX default)
  const float* W        = (const float*)d_in[2];
  const float* b        = (const float*)d_in[3];
  float*       out      = (float*)d_out;

  const int B = in_sizes[1];                     // 4096 segments
  const int T = in_sizes[0] / 256;               // total node rows
  const int chunk = (T + NWAVES - 1) / NWAVES;   // rows per wave (~64, uniform)

  int*   offsets = (int*)d_ws;                           // (B+1) ints
  float* seg_acc = (float*)((char*)d_ws + 32768);        // B*4 floats

  seg_offsets_kernel<<<1, SCAN_DIM, 0, stream>>>(node_num, offsets, seg_acc, B);
  proj_acc_kernel<<<NWAVES, 64, 0, stream>>>(x, offsets, W, seg_acc, B, T, chunk);
  finish_kernel<<<(B + 255) / 256, 256, 0, stream>>>(seg_acc, node_num, b, out, B);
}